// Round 1
// baseline (6383.442 us; speedup 1.0000x reference)
//
#include <hip/hip_runtime.h>
#include <hip/hip_bf16.h>

#define HID   512
#define SEQ   1024
#define WGD   16          // workgroups per LSTM direction
#define GATES 2048        // 4*HID

// ---------------------------------------------------------------- helpers
__device__ __forceinline__ float sigm(float x) {
    return 1.f / (1.f + __expf(-x));
}
__device__ __forceinline__ float tanh_fast(float x) {
    float ax = fabsf(x);
    float e  = __expf(-2.f * ax);
    float t  = (1.f - e) * __builtin_amdgcn_rcpf(1.f + e);
    return copysignf(t, x);
}
__device__ __forceinline__ float bcast(float v, int l) {
    return __uint_as_float((unsigned)__builtin_amdgcn_readlane((int)__float_as_uint(v), l));
}

// ---------------------------------------------------------------- embedding
__global__ void embed_kernel(const int* __restrict__ wi, const int* __restrict__ pi,
                             const float* __restrict__ we, const float* __restrict__ pe,
                             float* __restrict__ x) {
    int i = blockIdx.x;          // token 0..1023
    int t = threadIdx.x;         // 128 threads
    const float* w = we + (size_t)wi[i] * 300;
    const float* p = pe + (size_t)pi[i] * 100;
    float* xo = x + (size_t)i * 400;
    for (int c = t; c < 300; c += 128) xo[c]       = w[c];
    for (int c = t; c < 100; c += 128) xo[300 + c] = p[c];
}

// ---------------------------------------------------------------- fp32 GEMM: C[M,N] = A[M,K] @ B[N,K]^T + bias[N]
// M,N multiples of 64; K multiple of 16. 256 threads, 64x64 tile, 4x4/thread.
__global__ __launch_bounds__(256)
void gemm_bias(const float* __restrict__ A, const float* __restrict__ B,
               const float* __restrict__ bias, float* __restrict__ C,
               int M, int N, int K, int lda, int ldb, int ldc) {
    __shared__ float As[64 * 17];
    __shared__ float Bs[64 * 17];
    const int tid  = threadIdx.x;
    const int bn   = blockIdx.x, bm = blockIdx.y;
    const int tj   = tid & 15, ti = tid >> 4;
    const int lrow = tid >> 2;
    const int lk4  = (tid & 3) << 2;
    float acc[4][4] = {};

    for (int kt = 0; kt < K; kt += 16) {
        float4 av = *(const float4*)(A + (size_t)(bm * 64 + lrow) * lda + kt + lk4);
        float4 bv = *(const float4*)(B + (size_t)(bn * 64 + lrow) * ldb + kt + lk4);
        As[lrow * 17 + lk4 + 0] = av.x; As[lrow * 17 + lk4 + 1] = av.y;
        As[lrow * 17 + lk4 + 2] = av.z; As[lrow * 17 + lk4 + 3] = av.w;
        Bs[lrow * 17 + lk4 + 0] = bv.x; Bs[lrow * 17 + lk4 + 1] = bv.y;
        Bs[lrow * 17 + lk4 + 2] = bv.z; Bs[lrow * 17 + lk4 + 3] = bv.w;
        __syncthreads();
        #pragma unroll
        for (int k = 0; k < 16; ++k) {
            float a0 = As[(ti * 4 + 0) * 17 + k];
            float a1 = As[(ti * 4 + 1) * 17 + k];
            float a2 = As[(ti * 4 + 2) * 17 + k];
            float a3 = As[(ti * 4 + 3) * 17 + k];
            float b0 = Bs[(tj * 4 + 0) * 17 + k];
            float b1 = Bs[(tj * 4 + 1) * 17 + k];
            float b2_ = Bs[(tj * 4 + 2) * 17 + k];
            float b3 = Bs[(tj * 4 + 3) * 17 + k];
            acc[0][0] = fmaf(a0, b0, acc[0][0]); acc[0][1] = fmaf(a0, b1, acc[0][1]);
            acc[0][2] = fmaf(a0, b2_, acc[0][2]); acc[0][3] = fmaf(a0, b3, acc[0][3]);
            acc[1][0] = fmaf(a1, b0, acc[1][0]); acc[1][1] = fmaf(a1, b1, acc[1][1]);
            acc[1][2] = fmaf(a1, b2_, acc[1][2]); acc[1][3] = fmaf(a1, b3, acc[1][3]);
            acc[2][0] = fmaf(a2, b0, acc[2][0]); acc[2][1] = fmaf(a2, b1, acc[2][1]);
            acc[2][2] = fmaf(a2, b2_, acc[2][2]); acc[2][3] = fmaf(a2, b3, acc[2][3]);
            acc[3][0] = fmaf(a3, b0, acc[3][0]); acc[3][1] = fmaf(a3, b1, acc[3][1]);
            acc[3][2] = fmaf(a3, b2_, acc[3][2]); acc[3][3] = fmaf(a3, b3, acc[3][3]);
        }
        __syncthreads();
    }
    const int n0 = bn * 64 + tj * 4;
    float bb0 = 0.f, bb1 = 0.f, bb2 = 0.f, bb3 = 0.f;
    if (bias) { bb0 = bias[n0]; bb1 = bias[n0 + 1]; bb2 = bias[n0 + 2]; bb3 = bias[n0 + 3]; }
    #pragma unroll
    for (int i = 0; i < 4; ++i) {
        float4 o;
        o.x = acc[i][0] + bb0; o.y = acc[i][1] + bb1;
        o.z = acc[i][2] + bb2; o.w = acc[i][3] + bb3;
        *(float4*)(C + (size_t)(bm * 64 + ti * 4 + i) * ldc + n0) = o;
    }
}

// ---------------------------------------------------------------- persistent bidirectional LSTM layer
// 32 WGs x 512 threads. WGs [0,16): forward dir; [16,32): reverse dir.
// Each WG owns 32 hidden units -> 128 rows of Whh, weights held in VGPRs
// (128 floats/lane). Per step: 1 device-scope barrier per direction.
__global__ __launch_bounds__(512)
void lstm_layer(const float* __restrict__ Zf, const float* __restrict__ Zr,
                const float* __restrict__ WhhF, const float* __restrict__ WhhR,
                float* __restrict__ Hout,   // [SEQ][2*HID]; fwd cols 0..511, rev 512..1023
                unsigned* cntF, unsigned* cntR) {
    const int dir = blockIdx.x >> 4;
    const int wg  = blockIdx.x & 15;
    const float* __restrict__ Z   = dir ? Zr   : Zf;
    const float* __restrict__ Whh = dir ? WhhR : WhhF;
    unsigned* cnt   = dir ? cntR : cntF;
    const int colOff = dir ? HID : 0;

    const int tid   = threadIdx.x;
    const int wave  = tid >> 6;      // 0..7
    const int lane  = tid & 63;
    const int chunk = wave & 3;      // k-chunk (128 wide)
    const int rb    = wave >> 2;     // row block 0/1
    const int lr    = rb * 64 + lane;        // local row 0..127
    const int g     = lr >> 5;               // gate 0..3 (i,f,g,o)
    const int jj    = lr & 31;
    const int grow  = g * HID + wg * 32 + jj;  // row in Whh [2048]

    // load this lane's 128 recurrent weights into registers (once)
    float w[128];
    {
        const float4* wp = (const float4*)(Whh + (size_t)grow * HID + chunk * 128);
        #pragma unroll
        for (int q = 0; q < 32; ++q) {
            float4 v = wp[q];
            w[4 * q] = v.x; w[4 * q + 1] = v.y; w[4 * q + 2] = v.z; w[4 * q + 3] = v.w;
        }
    }

    __shared__ float part[128 * 5];
    float cval = 0.f;    // cell state (only meaningful for tid < 32)

    for (int s = 0; s < SEQ; ++s) {
        const int t = dir ? (SEQ - 1 - s) : s;

        // fetch previous h (device-coherent loads) into lane-distributed regs
        float h0v = 0.f, h1v = 0.f;
        if (s > 0) {
            const int tp = dir ? (t + 1) : (t - 1);
            unsigned* hp = (unsigned*)(Hout + (size_t)tp * (2 * HID) + colOff + chunk * 128);
            h0v = __uint_as_float(__hip_atomic_load(hp + lane,      __ATOMIC_RELAXED, __HIP_MEMORY_SCOPE_AGENT));
            h1v = __uint_as_float(__hip_atomic_load(hp + 64 + lane, __ATOMIC_RELAXED, __HIP_MEMORY_SCOPE_AGENT));
        }
        // prefetch precomputed input projection for gate threads
        float zin0 = 0.f, zin1 = 0.f, zin2 = 0.f, zin3 = 0.f;
        if (tid < 32) {
            const float* zp = Z + (size_t)t * GATES + wg * 32 + tid;
            zin0 = zp[0]; zin1 = zp[512]; zin2 = zp[1024]; zin3 = zp[1536];
        }
        // matvec: acc = Whh[grow][chunk*128 .. +127] . h_prev[chunk*128 ..]
        float acc = 0.f;
        if (s > 0) {
            #pragma unroll
            for (int m = 0; m < 64; ++m) acc = fmaf(w[m],      bcast(h0v, m), acc);
            #pragma unroll
            for (int m = 0; m < 64; ++m) acc = fmaf(w[64 + m], bcast(h1v, m), acc);
        }
        part[lr * 5 + chunk] = acc;
        __syncthreads();

        if (tid < 32) {
            const float* p0 = &part[(0 * 32 + tid) * 5];
            const float* p1 = &part[(1 * 32 + tid) * 5];
            const float* p2 = &part[(2 * 32 + tid) * 5];
            const float* p3 = &part[(3 * 32 + tid) * 5];
            float zi = zin0 + p0[0] + p0[1] + p0[2] + p0[3];
            float zf = zin1 + p1[0] + p1[1] + p1[2] + p1[3];
            float zg = zin2 + p2[0] + p2[1] + p2[2] + p2[3];
            float zo = zin3 + p3[0] + p3[1] + p3[2] + p3[3];
            float ig = sigm(zi), fg = sigm(zf), gg = tanh_fast(zg), og = sigm(zo);
            cval = fg * cval + ig * gg;
            float hv = og * tanh_fast(cval);
            __hip_atomic_store((unsigned*)(Hout + (size_t)t * (2 * HID) + colOff + wg * 32 + tid),
                               __float_as_uint(hv), __ATOMIC_RELAXED, __HIP_MEMORY_SCOPE_AGENT);
        }
        __syncthreads();   // drains vmcnt: all h stores device-visible before arrive

        if (tid == 0) {
            __hip_atomic_fetch_add(cnt, 1u, __ATOMIC_RELEASE, __HIP_MEMORY_SCOPE_AGENT);
            const unsigned tgt = (unsigned)(WGD * (s + 1));
            while (__hip_atomic_load(cnt, __ATOMIC_ACQUIRE, __HIP_MEMORY_SCOPE_AGENT) < tgt)
                __builtin_amdgcn_s_sleep(2);
        }
        __syncthreads();
    }
}

// ---------------------------------------------------------------- pairwise MLP scores
// scores[i,j] = sum_m tanh(a[i,m] + b[j,m]) * w2[m] + b2   (bmlp1 folded into a)
__global__ __launch_bounds__(256)
void pairwise_kernel(const float* __restrict__ Ah, const float* __restrict__ Bd,
                     const float* __restrict__ w2, const float* __restrict__ b2,
                     float* __restrict__ out) {
    __shared__ __align__(16) float at[16 * 260];
    __shared__ __align__(16) float bt[16 * 260];
    __shared__ __align__(16) float wl[256];
    const int tid = threadIdx.x;
    const int i0 = blockIdx.y * 16, j0 = blockIdx.x * 16;
    for (int u = tid; u < 16 * 256; u += 256) {
        int r = u >> 8, m = u & 255;
        at[r * 260 + m] = Ah[(size_t)(i0 + r) * 256 + m];
        bt[r * 260 + m] = Bd[(size_t)(j0 + r) * 256 + m];
    }
    wl[tid] = w2[tid];
    __syncthreads();
    const int tj = tid & 15, ti = tid >> 4;
    float acc = b2[0];
    #pragma unroll 2
    for (int m = 0; m < 256; m += 4) {
        float4 a4 = *(const float4*)&at[ti * 260 + m];
        float4 b4 = *(const float4*)&bt[tj * 260 + m];
        float4 w4 = *(const float4*)&wl[m];
        acc += tanh_fast(a4.x + b4.x) * w4.x;
        acc += tanh_fast(a4.y + b4.y) * w4.y;
        acc += tanh_fast(a4.z + b4.z) * w4.z;
        acc += tanh_fast(a4.w + b4.w) * w4.w;
    }
    out[(size_t)(i0 + ti) * 1024 + (j0 + tj)] = acc;
}

// ---------------------------------------------------------------- launch
extern "C" void kernel_launch(void* const* d_in, const int* in_sizes, int n_in,
                              void* d_out, int out_size, void* d_ws, size_t ws_size,
                              hipStream_t stream) {
    const int*   wi    = (const int*)  d_in[0];
    const int*   pi    = (const int*)  d_in[1];
    const float* we    = (const float*)d_in[2];
    const float* pe    = (const float*)d_in[3];
    const float* wih0f = (const float*)d_in[4];
    const float* whh0f = (const float*)d_in[5];
    const float* b0f   = (const float*)d_in[6];
    const float* wih0r = (const float*)d_in[7];
    const float* whh0r = (const float*)d_in[8];
    const float* b0r   = (const float*)d_in[9];
    const float* wih1f = (const float*)d_in[10];
    const float* whh1f = (const float*)d_in[11];
    const float* b1f   = (const float*)d_in[12];
    const float* wih1r = (const float*)d_in[13];
    const float* whh1r = (const float*)d_in[14];
    const float* b1r   = (const float*)d_in[15];
    const float* W1    = (const float*)d_in[16];
    const float* bmlp1 = (const float*)d_in[17];
    const float* w2    = (const float*)d_in[18];
    const float* b2    = (const float*)d_in[19];
    float* out = (float*)d_out;

    char* wsb = (char*)d_ws;
    unsigned* c0 = (unsigned*)(wsb + 0);
    unsigned* c1 = (unsigned*)(wsb + 128);
    unsigned* c2 = (unsigned*)(wsb + 256);
    unsigned* c3 = (unsigned*)(wsb + 384);
    float* x  = (float*)(wsb + 512);          // 1024*400
    float* zA = x  + (size_t)1024 * 400;      // 1024*2048
    float* zB = zA + (size_t)1024 * 2048;     // 1024*2048
    float* h0 = zB + (size_t)1024 * 2048;     // 1024*1024
    float* h1 = h0 + (size_t)1024 * 1024;     // 1024*1024
    float* aH = h1 + (size_t)1024 * 1024;     // 1024*256
    float* bD = aH + (size_t)1024 * 256;      // 1024*256

    hipMemsetAsync(d_ws, 0, 512, stream);     // zero barrier counters

    embed_kernel<<<dim3(1024), dim3(128), 0, stream>>>(wi, pi, we, pe, x);

    // layer-0 input projections: [1024,400] @ [2048,400]^T
    gemm_bias<<<dim3(32, 16), dim3(256), 0, stream>>>(x, wih0f, b0f, zA, 1024, 2048, 400, 400, 400, 2048);
    gemm_bias<<<dim3(32, 16), dim3(256), 0, stream>>>(x, wih0r, b0r, zB, 1024, 2048, 400, 400, 400, 2048);

    lstm_layer<<<dim3(32), dim3(512), 0, stream>>>(zA, zB, whh0f, whh0r, h0, c0, c1);

    // layer-1 input projections: [1024,1024] @ [2048,1024]^T
    gemm_bias<<<dim3(32, 16), dim3(256), 0, stream>>>(h0, wih1f, b1f, zA, 1024, 2048, 1024, 1024, 1024, 2048);
    gemm_bias<<<dim3(32, 16), dim3(256), 0, stream>>>(h0, wih1r, b1r, zB, 1024, 2048, 1024, 1024, 1024, 2048);

    lstm_layer<<<dim3(32), dim3(512), 0, stream>>>(zA, zB, whh1f, whh1r, h1, c2, c3);

    // head/dep projections: [1024,1024] @ [256,1024]^T (W1 split, bmlp1 folded into aH)
    gemm_bias<<<dim3(4, 16), dim3(256), 0, stream>>>(h1, W1,        bmlp1,   aH, 1024, 256, 1024, 1024, 2048, 256);
    gemm_bias<<<dim3(4, 16), dim3(256), 0, stream>>>(h1, W1 + 1024, nullptr, bD, 1024, 256, 1024, 1024, 2048, 256);

    pairwise_kernel<<<dim3(64, 64), dim3(256), 0, stream>>>(aH, bD, w2, b2, out);
}

// Round 2
// 4840.188 us; speedup vs baseline: 1.3188x; 1.3188x over previous
//
#include <hip/hip_runtime.h>
#include <hip/hip_bf16.h>

#define HID   512
#define SEQ   1024
#define WGD   16          // workgroups per LSTM direction
#define GATES 2048        // 4*HID

// ---------------------------------------------------------------- helpers
__device__ __forceinline__ float sigm(float x) {
    return 1.f / (1.f + __expf(-x));
}
__device__ __forceinline__ float tanh_fast(float x) {
    float ax = fabsf(x);
    float e  = __expf(-2.f * ax);
    float t  = (1.f - e) * __builtin_amdgcn_rcpf(1.f + e);
    return copysignf(t, x);
}
__device__ __forceinline__ float bcast(float v, int l) {
    return __uint_as_float((unsigned)__builtin_amdgcn_readlane((int)__float_as_uint(v), l));
}

// ---------------------------------------------------------------- embedding
__global__ void embed_kernel(const int* __restrict__ wi, const int* __restrict__ pi,
                             const float* __restrict__ we, const float* __restrict__ pe,
                             float* __restrict__ x) {
    int i = blockIdx.x;          // token 0..1023
    int t = threadIdx.x;         // 128 threads
    const float* w = we + (size_t)wi[i] * 300;
    const float* p = pe + (size_t)pi[i] * 100;
    float* xo = x + (size_t)i * 400;
    for (int c = t; c < 300; c += 128) xo[c]       = w[c];
    for (int c = t; c < 100; c += 128) xo[300 + c] = p[c];
}

// ---------------------------------------------------------------- fp32 GEMM: C[M,N] = A[M,K] @ B[N,K]^T + bias[N]
__global__ __launch_bounds__(256)
void gemm_bias(const float* __restrict__ A, const float* __restrict__ B,
               const float* __restrict__ bias, float* __restrict__ C,
               int M, int N, int K, int lda, int ldb, int ldc) {
    __shared__ float As[64 * 17];
    __shared__ float Bs[64 * 17];
    const int tid  = threadIdx.x;
    const int bn   = blockIdx.x, bm = blockIdx.y;
    const int tj   = tid & 15, ti = tid >> 4;
    const int lrow = tid >> 2;
    const int lk4  = (tid & 3) << 2;
    float acc[4][4] = {};

    for (int kt = 0; kt < K; kt += 16) {
        float4 av = *(const float4*)(A + (size_t)(bm * 64 + lrow) * lda + kt + lk4);
        float4 bv = *(const float4*)(B + (size_t)(bn * 64 + lrow) * ldb + kt + lk4);
        As[lrow * 17 + lk4 + 0] = av.x; As[lrow * 17 + lk4 + 1] = av.y;
        As[lrow * 17 + lk4 + 2] = av.z; As[lrow * 17 + lk4 + 3] = av.w;
        Bs[lrow * 17 + lk4 + 0] = bv.x; Bs[lrow * 17 + lk4 + 1] = bv.y;
        Bs[lrow * 17 + lk4 + 2] = bv.z; Bs[lrow * 17 + lk4 + 3] = bv.w;
        __syncthreads();
        #pragma unroll
        for (int k = 0; k < 16; ++k) {
            float a0 = As[(ti * 4 + 0) * 17 + k];
            float a1 = As[(ti * 4 + 1) * 17 + k];
            float a2 = As[(ti * 4 + 2) * 17 + k];
            float a3 = As[(ti * 4 + 3) * 17 + k];
            float b0 = Bs[(tj * 4 + 0) * 17 + k];
            float b1 = Bs[(tj * 4 + 1) * 17 + k];
            float b2_ = Bs[(tj * 4 + 2) * 17 + k];
            float b3 = Bs[(tj * 4 + 3) * 17 + k];
            acc[0][0] = fmaf(a0, b0, acc[0][0]); acc[0][1] = fmaf(a0, b1, acc[0][1]);
            acc[0][2] = fmaf(a0, b2_, acc[0][2]); acc[0][3] = fmaf(a0, b3, acc[0][3]);
            acc[1][0] = fmaf(a1, b0, acc[1][0]); acc[1][1] = fmaf(a1, b1, acc[1][1]);
            acc[1][2] = fmaf(a1, b2_, acc[1][2]); acc[1][3] = fmaf(a1, b3, acc[1][3]);
            acc[2][0] = fmaf(a2, b0, acc[2][0]); acc[2][1] = fmaf(a2, b1, acc[2][1]);
            acc[2][2] = fmaf(a2, b2_, acc[2][2]); acc[2][3] = fmaf(a2, b3, acc[2][3]);
            acc[3][0] = fmaf(a3, b0, acc[3][0]); acc[3][1] = fmaf(a3, b1, acc[3][1]);
            acc[3][2] = fmaf(a3, b2_, acc[3][2]); acc[3][3] = fmaf(a3, b3, acc[3][3]);
        }
        __syncthreads();
    }
    const int n0 = bn * 64 + tj * 4;
    float bb0 = 0.f, bb1 = 0.f, bb2 = 0.f, bb3 = 0.f;
    if (bias) { bb0 = bias[n0]; bb1 = bias[n0 + 1]; bb2 = bias[n0 + 2]; bb3 = bias[n0 + 3]; }
    #pragma unroll
    for (int i = 0; i < 4; ++i) {
        float4 o;
        o.x = acc[i][0] + bb0; o.y = acc[i][1] + bb1;
        o.z = acc[i][2] + bb2; o.w = acc[i][3] + bb3;
        *(float4*)(C + (size_t)(bm * 64 + ti * 4 + i) * ldc + n0) = o;
    }
}

// ---------------------------------------------------------------- persistent bidirectional LSTM layer
// 32 WGs x 512 threads. WGs [0,16): forward; [16,32): reverse. Each WG owns 32
// hidden units (128 gate rows of Whh), weights in registers (128/lane).
// Synchronization: h is exchanged as 64-bit (tag<<32|h) atomics — the data IS
// the flag. No counters, no release fences, one __syncthreads per step.
// Tags are layer-unique so Hpair can be reused across layers without clearing
// (the 0xAA workspace poison never matches a valid tag).
__global__ __launch_bounds__(512)
void lstm_layer(const float* __restrict__ Zf, const float* __restrict__ Zr,
                const float* __restrict__ WhhF, const float* __restrict__ WhhR,
                unsigned long long* __restrict__ Hpair, // [SEQ][2*HID] (tag|h)
                float* __restrict__ Hout,               // [SEQ][2*HID] plain fp32
                unsigned tagBase) {
    const int dir = blockIdx.x >> 4;
    const int wg  = blockIdx.x & 15;
    const float* __restrict__ Z   = dir ? Zr : Zf;
    const float* __restrict__ Whh = dir ? (WhhF + (size_t)GATES * HID) : WhhF; // WhhR passed contiguå? no — see launch
    unsigned long long* HP = Hpair;
    const int colOff = dir ? HID : 0;

    const int tid   = threadIdx.x;
    const int wave  = tid >> 6;      // 0..7
    const int lane  = tid & 63;
    const int chunk = wave & 3;      // k-chunk (128 wide)
    const int rb    = wave >> 2;     // row block 0/1
    const int lr    = rb * 64 + lane;          // local row 0..127
    const int g     = lr >> 5;                 // gate 0..3 (i,f,g,o)
    const int jj    = lr & 31;
    const int grow  = g * HID + wg * 32 + jj;  // row in Whh [2048]

    // load this lane's 128 recurrent weights (once)
    float w[128];
    {
        const float4* wp = (const float4*)(Whh + (size_t)grow * HID + chunk * 128);
        #pragma unroll
        for (int q = 0; q < 32; ++q) {
            float4 v = wp[q];
            w[4 * q] = v.x; w[4 * q + 1] = v.y; w[4 * q + 2] = v.z; w[4 * q + 3] = v.w;
        }
    }

    __shared__ float part[128 * 5];
    float cval = 0.f;    // cell state (tid < 32 only)

    for (int s = 0; s < SEQ; ++s) {
        const int t = dir ? (SEQ - 1 - s) : s;

        // prefetch input projection early (static data, overlaps the poll)
        float zin0 = 0.f, zin1 = 0.f, zin2 = 0.f, zin3 = 0.f;
        if (tid < 32) {
            const float* zp = Z + (size_t)t * GATES + wg * 32 + tid;
            zin0 = zp[0]; zin1 = zp[512]; zin2 = zp[1024]; zin3 = zp[1536];
        }

        float acc = 0.f;
        if (s > 0) {
            const int tp = dir ? (t + 1) : (t - 1);
            const unsigned expTag = tagBase + (unsigned)s - 1u;
            unsigned long long* hp = HP + (size_t)tp * (2 * HID) + colOff + chunk * 128;
            unsigned long long v0, v1;
            for (;;) {
                v0 = __hip_atomic_load(hp + lane,      __ATOMIC_RELAXED, __HIP_MEMORY_SCOPE_AGENT);
                v1 = __hip_atomic_load(hp + 64 + lane, __ATOMIC_RELAXED, __HIP_MEMORY_SCOPE_AGENT);
                int ok = ((unsigned)(v0 >> 32) == expTag) & ((unsigned)(v1 >> 32) == expTag);
                if (__all(ok)) break;
            }
            float h0v = __uint_as_float((unsigned)v0);
            float h1v = __uint_as_float((unsigned)v1);
            #pragma unroll
            for (int m = 0; m < 64; ++m) acc = fmaf(w[m],      bcast(h0v, m), acc);
            #pragma unroll
            for (int m = 0; m < 64; ++m) acc = fmaf(w[64 + m], bcast(h1v, m), acc);
        }
        part[lr * 5 + chunk] = acc;
        __syncthreads();

        if (tid < 32) {
            const float* p0 = &part[(0 * 32 + tid) * 5];
            const float* p1 = &part[(1 * 32 + tid) * 5];
            const float* p2 = &part[(2 * 32 + tid) * 5];
            const float* p3 = &part[(3 * 32 + tid) * 5];
            float zi = zin0 + p0[0] + p0[1] + p0[2] + p0[3];
            float zf = zin1 + p1[0] + p1[1] + p1[2] + p1[3];
            float zg = zin2 + p2[0] + p2[1] + p2[2] + p2[3];
            float zo = zin3 + p3[0] + p3[1] + p3[2] + p3[3];
            float ig = sigm(zi), fg = sigm(zf), gg = tanh_fast(zg), og = sigm(zo);
            cval = fg * cval + ig * gg;
            float hv = og * tanh_fast(cval);
            const size_t oidx = (size_t)t * (2 * HID) + colOff + wg * 32 + tid;
            unsigned long long pk = ((unsigned long long)(tagBase + (unsigned)s) << 32)
                                  | (unsigned long long)__float_as_uint(hv);
            __hip_atomic_store(HP + oidx, pk, __ATOMIC_RELAXED, __HIP_MEMORY_SCOPE_AGENT);
            Hout[oidx] = hv;   // plain copy for downstream GEMMs (kernel-boundary flush)
        }
        // no second barrier: a consumer can only reach its part[] write for
        // step s+1 after observing tag s (own WG included), which the producer
        // stores only after reading part[] for step s.
    }
}

// ---------------------------------------------------------------- pairwise MLP scores
__global__ __launch_bounds__(256)
void pairwise_kernel(const float* __restrict__ Ah, const float* __restrict__ Bd,
                     const float* __restrict__ w2, const float* __restrict__ b2,
                     float* __restrict__ out) {
    __shared__ __align__(16) float at[16 * 260];
    __shared__ __align__(16) float bt[16 * 260];
    __shared__ __align__(16) float wl[256];
    const int tid = threadIdx.x;
    const int i0 = blockIdx.y * 16, j0 = blockIdx.x * 16;
    for (int u = tid; u < 16 * 256; u += 256) {
        int r = u >> 8, m = u & 255;
        at[r * 260 + m] = Ah[(size_t)(i0 + r) * 256 + m];
        bt[r * 260 + m] = Bd[(size_t)(j0 + r) * 256 + m];
    }
    wl[tid] = w2[tid];
    __syncthreads();
    const int tj = tid & 15, ti = tid >> 4;
    float acc = b2[0];
    #pragma unroll 2
    for (int m = 0; m < 256; m += 4) {
        float4 a4 = *(const float4*)&at[ti * 260 + m];
        float4 b4 = *(const float4*)&bt[tj * 260 + m];
        float4 w4 = *(const float4*)&wl[m];
        acc += tanh_fast(a4.x + b4.x) * w4.x;
        acc += tanh_fast(a4.y + b4.y) * w4.y;
        acc += tanh_fast(a4.z + b4.z) * w4.z;
        acc += tanh_fast(a4.w + b4.w) * w4.w;
    }
    out[(size_t)(i0 + ti) * 1024 + (j0 + tj)] = acc;
}

// ---------------------------------------------------------------- launch
extern "C" void kernel_launch(void* const* d_in, const int* in_sizes, int n_in,
                              void* d_out, int out_size, void* d_ws, size_t ws_size,
                              hipStream_t stream) {
    const int*   wi    = (const int*)  d_in[0];
    const int*   pi    = (const int*)  d_in[1];
    const float* we    = (const float*)d_in[2];
    const float* pe    = (const float*)d_in[3];
    const float* wih0f = (const float*)d_in[4];
    const float* whh0f = (const float*)d_in[5];
    const float* b0f   = (const float*)d_in[6];
    const float* wih0r = (const float*)d_in[7];
    const float* whh0r = (const float*)d_in[8];
    const float* b0r   = (const float*)d_in[9];
    const float* wih1f = (const float*)d_in[10];
    const float* whh1f = (const float*)d_in[11];
    const float* b1f   = (const float*)d_in[12];
    const float* wih1r = (const float*)d_in[13];
    const float* whh1r = (const float*)d_in[14];
    const float* b1r   = (const float*)d_in[15];
    const float* W1    = (const float*)d_in[16];
    const float* bmlp1 = (const float*)d_in[17];
    const float* w2    = (const float*)d_in[18];
    const float* b2    = (const float*)d_in[19];
    float* out = (float*)d_out;

    char* wsb = (char*)d_ws;
    float* x  = (float*)(wsb + 512);          // 1024*400
    float* zA = x  + (size_t)1024 * 400;      // 1024*2048
    float* zB = zA + (size_t)1024 * 2048;     // 1024*2048
    float* h0 = zB + (size_t)1024 * 2048;     // 1024*1024
    float* h1 = h0 + (size_t)1024 * 1024;     // 1024*1024
    float* aH = h1 + (size_t)1024 * 1024;     // 1024*256
    float* bD = aH + (size_t)1024 * 256;      // 1024*256
    unsigned long long* Hpair = (unsigned long long*)(bD + (size_t)1024 * 256); // 1024*1024 u64

    embed_kernel<<<dim3(1024), dim3(128), 0, stream>>>(wi, pi, we, pe, x);

    // layer-0 input projections: [1024,400] @ [2048,400]^T
    gemm_bias<<<dim3(32, 16), dim3(256), 0, stream>>>(x, wih0f, b0f, zA, 1024, 2048, 400, 400, 400, 2048);
    gemm_bias<<<dim3(32, 16), dim3(256), 0, stream>>>(x, wih0r, b0r, zB, 1024, 2048, 400, 400, 400, 2048);

    // NOTE: lstm_layer derives WhhR = WhhF + GATES*HID only if the two weight
    // arrays were contiguous — they are separate inputs, so pass both and pick
    // inside. (See kernel: dir picks between the two pointers.)
    // To keep the kernel signature honest we pass WhhF with reverse at +offset
    // only when they ARE contiguous; here they are not, so we instead launch
    // with a trick: copy not needed — kernel uses `dir ? (WhhF + GATES*HID)`.
    // We therefore stage both weight matrices contiguously once per call.
    {
        // contiguous staging buffer after Hpair: 2 * 2048*512 floats per layer
        float* wstage = (float*)(Hpair + (size_t)1024 * 1024);
        hipMemcpyAsync(wstage,                       whh0f, sizeof(float) * GATES * HID, hipMemcpyDeviceToDevice, stream);
        hipMemcpyAsync(wstage + (size_t)GATES * HID, whh0r, sizeof(float) * GATES * HID, hipMemcpyDeviceToDevice, stream);
        lstm_layer<<<dim3(32), dim3(512), 0, stream>>>(zA, zB, wstage, nullptr, Hpair, h0, 1u);

        gemm_bias<<<dim3(32, 16), dim3(256), 0, stream>>>(h0, wih1f, b1f, zA, 1024, 2048, 1024, 1024, 1024, 2048);
        gemm_bias<<<dim3(32, 16), dim3(256), 0, stream>>>(h0, wih1r, b1r, zB, 1024, 2048, 1024, 1024, 1024, 2048);

        hipMemcpyAsync(wstage,                       whh1f, sizeof(float) * GATES * HID, hipMemcpyDeviceToDevice, stream);
        hipMemcpyAsync(wstage + (size_t)GATES * HID, whh1r, sizeof(float) * GATES * HID, hipMemcpyDeviceToDevice, stream);
        lstm_layer<<<dim3(32), dim3(512), 0, stream>>>(zA, zB, wstage, nullptr, Hpair, h1, 8192u);
    }

    // head/dep projections: [1024,1024] @ [256,1024]^T (bmlp1 folded into aH)
    gemm_bias<<<dim3(4, 16), dim3(256), 0, stream>>>(h1, W1,        bmlp1,   aH, 1024, 256, 1024, 1024, 2048, 256);
    gemm_bias<<<dim3(4, 16), dim3(256), 0, stream>>>(h1, W1 + 1024, nullptr, bD, 1024, 256, 1024, 1024, 2048, 256);

    pairwise_kernel<<<dim3(64, 64), dim3(256), 0, stream>>>(aH, bD, w2, b2, out);
}

// Round 3
// 3752.369 us; speedup vs baseline: 1.7012x; 1.2899x over previous
//
#include <hip/hip_runtime.h>
#include <hip/hip_bf16.h>

#define HID   512
#define SEQ   1024
#define WGD   32          // workgroups per LSTM direction
#define GATES 2048        // 4*HID

// ---------------------------------------------------------------- helpers
__device__ __forceinline__ float sigm(float x) {
    return 1.f / (1.f + __expf(-x));
}
__device__ __forceinline__ float tanh_fast(float x) {
    float ax = fabsf(x);
    float e  = __expf(-2.f * ax);
    float t  = (1.f - e) * __builtin_amdgcn_rcpf(1.f + e);
    return copysignf(t, x);
}
__device__ __forceinline__ float bcast(float v, int l) {
    return __uint_as_float((unsigned)__builtin_amdgcn_readlane((int)__float_as_uint(v), l));
}

// ---------------------------------------------------------------- embedding
__global__ void embed_kernel(const int* __restrict__ wi, const int* __restrict__ pi,
                             const float* __restrict__ we, const float* __restrict__ pe,
                             float* __restrict__ x) {
    int i = blockIdx.x;          // token 0..1023
    int t = threadIdx.x;         // 128 threads
    const float* w = we + (size_t)wi[i] * 300;
    const float* p = pe + (size_t)pi[i] * 100;
    float* xo = x + (size_t)i * 400;
    for (int c = t; c < 300; c += 128) xo[c]       = w[c];
    for (int c = t; c < 100; c += 128) xo[300 + c] = p[c];
}

// ---------------------------------------------------------------- fp32 GEMM: C[M,N] = A[M,K] @ B[N,K]^T + bias[N]
__global__ __launch_bounds__(256)
void gemm_bias(const float* __restrict__ A, const float* __restrict__ B,
               const float* __restrict__ bias, float* __restrict__ C,
               int M, int N, int K, int lda, int ldb, int ldc) {
    __shared__ float As[64 * 17];
    __shared__ float Bs[64 * 17];
    const int tid  = threadIdx.x;
    const int bn   = blockIdx.x, bm = blockIdx.y;
    const int tj   = tid & 15, ti = tid >> 4;
    const int lrow = tid >> 2;
    const int lk4  = (tid & 3) << 2;
    float acc[4][4] = {};

    for (int kt = 0; kt < K; kt += 16) {
        float4 av = *(const float4*)(A + (size_t)(bm * 64 + lrow) * lda + kt + lk4);
        float4 bv = *(const float4*)(B + (size_t)(bn * 64 + lrow) * ldb + kt + lk4);
        As[lrow * 17 + lk4 + 0] = av.x; As[lrow * 17 + lk4 + 1] = av.y;
        As[lrow * 17 + lk4 + 2] = av.z; As[lrow * 17 + lk4 + 3] = av.w;
        Bs[lrow * 17 + lk4 + 0] = bv.x; Bs[lrow * 17 + lk4 + 1] = bv.y;
        Bs[lrow * 17 + lk4 + 2] = bv.z; Bs[lrow * 17 + lk4 + 3] = bv.w;
        __syncthreads();
        #pragma unroll
        for (int k = 0; k < 16; ++k) {
            float a0 = As[(ti * 4 + 0) * 17 + k];
            float a1 = As[(ti * 4 + 1) * 17 + k];
            float a2 = As[(ti * 4 + 2) * 17 + k];
            float a3 = As[(ti * 4 + 3) * 17 + k];
            float b0 = Bs[(tj * 4 + 0) * 17 + k];
            float b1 = Bs[(tj * 4 + 1) * 17 + k];
            float b2_ = Bs[(tj * 4 + 2) * 17 + k];
            float b3 = Bs[(tj * 4 + 3) * 17 + k];
            acc[0][0] = fmaf(a0, b0, acc[0][0]); acc[0][1] = fmaf(a0, b1, acc[0][1]);
            acc[0][2] = fmaf(a0, b2_, acc[0][2]); acc[0][3] = fmaf(a0, b3, acc[0][3]);
            acc[1][0] = fmaf(a1, b0, acc[1][0]); acc[1][1] = fmaf(a1, b1, acc[1][1]);
            acc[1][2] = fmaf(a1, b2_, acc[1][2]); acc[1][3] = fmaf(a1, b3, acc[1][3]);
            acc[2][0] = fmaf(a2, b0, acc[2][0]); acc[2][1] = fmaf(a2, b1, acc[2][1]);
            acc[2][2] = fmaf(a2, b2_, acc[2][2]); acc[2][3] = fmaf(a2, b3, acc[2][3]);
            acc[3][0] = fmaf(a3, b0, acc[3][0]); acc[3][1] = fmaf(a3, b1, acc[3][1]);
            acc[3][2] = fmaf(a3, b2_, acc[3][2]); acc[3][3] = fmaf(a3, b3, acc[3][3]);
        }
        __syncthreads();
    }
    const int n0 = bn * 64 + tj * 4;
    float bb0 = 0.f, bb1 = 0.f, bb2 = 0.f, bb3 = 0.f;
    if (bias) { bb0 = bias[n0]; bb1 = bias[n0 + 1]; bb2 = bias[n0 + 2]; bb3 = bias[n0 + 3]; }
    #pragma unroll
    for (int i = 0; i < 4; ++i) {
        float4 o;
        o.x = acc[i][0] + bb0; o.y = acc[i][1] + bb1;
        o.z = acc[i][2] + bb2; o.w = acc[i][3] + bb3;
        *(float4*)(C + (size_t)(bm * 64 + ti * 4 + i) * ldc + n0) = o;
    }
}

// ---------------------------------------------------------------- persistent bidirectional LSTM layer
// 64 WGs x 512 threads. WGs [0,32): forward; [32,64): reverse. Each WG owns 16
// hidden units = 64 gate rows. Within a WG: lane = gate row (0..63), wave =
// 64-wide k-chunk (8 waves cover K=512). 64 weights/lane in registers.
// h exchanged as 64-bit (tag<<32|bits) relaxed AGENT atomics: data IS the flag.
// Each wave's poll also checks its OWN WG's tag — that ordering protects the
// LDS `part` buffer reuse (producer wave 0 stores the tag only after it has
// read `part`), so one __syncthreads per step suffices.
__global__ __launch_bounds__(512)
void lstm_layer(const float* __restrict__ Zf, const float* __restrict__ Zr,
                const float* __restrict__ WhhF, const float* __restrict__ WhhR,
                unsigned long long* __restrict__ Hpair, // [SEQ][2*HID] (tag|h)
                float* __restrict__ Hout,               // [SEQ][2*HID] plain fp32
                unsigned tagBase) {
    const int dir = blockIdx.x >> 5;
    const int wg  = blockIdx.x & 31;
    const float* __restrict__ Z   = dir ? Zr   : Zf;
    const float* __restrict__ Whh = dir ? WhhR : WhhF;
    const int colOff = dir ? HID : 0;

    const int tid  = threadIdx.x;
    const int wave = tid >> 6;        // k-chunk 0..7 (covers h[64*wave .. +64))
    const int lane = tid & 63;        // local gate row 0..63
    const int g    = lane >> 4;       // gate 0..3 (i,f,g,o)
    const int jj   = lane & 15;       // local hidden unit 0..15
    const int grow = g * HID + wg * 16 + jj;   // row in Whh [2048 x 512]

    // this lane's 64 recurrent weights (k = wave*64 .. +64)
    float w[64];
    {
        const float4* wp = (const float4*)(Whh + (size_t)grow * HID + wave * 64);
        #pragma unroll
        for (int q = 0; q < 16; ++q) {
            float4 v = wp[q];
            w[4 * q] = v.x; w[4 * q + 1] = v.y; w[4 * q + 2] = v.z; w[4 * q + 3] = v.w;
        }
    }

    __shared__ float part[8 * 65];
    float cval = 0.f;                 // cell state (wave 0, lanes 0..15)

    for (int s = 0; s < SEQ; ++s) {
        const int t = dir ? (SEQ - 1 - s) : s;

        // wave 0 prefetches this row's input-projection z (overlaps the poll)
        float zin = 0.f;
        if (wave == 0) zin = Z[(size_t)t * GATES + grow];

        float acc = 0.f;
        if (s > 0) {
            const int tp = dir ? (t + 1) : (t - 1);
            const unsigned expTag = tagBase + (unsigned)s - 1u;
            unsigned long long* hp = Hpair + (size_t)tp * (2 * HID) + colOff + wave * 64;
            unsigned long long* op = Hpair + (size_t)tp * (2 * HID) + colOff + wg * 16 + jj;
            unsigned long long v, o;
            for (;;) {
                v = __hip_atomic_load(hp + lane, __ATOMIC_RELAXED, __HIP_MEMORY_SCOPE_AGENT);
                o = __hip_atomic_load(op,        __ATOMIC_RELAXED, __HIP_MEMORY_SCOPE_AGENT);
                int ok = ((unsigned)(v >> 32) == expTag) & ((unsigned)(o >> 32) == expTag);
                if (__all(ok)) break;
            }
            float hv = __uint_as_float((unsigned)v);   // h[64*wave + lane]
            float a0 = 0.f, a1 = 0.f, a2 = 0.f, a3 = 0.f;
            #pragma unroll
            for (int m = 0; m < 64; m += 4) {
                a0 = fmaf(w[m + 0], bcast(hv, m + 0), a0);
                a1 = fmaf(w[m + 1], bcast(hv, m + 1), a1);
                a2 = fmaf(w[m + 2], bcast(hv, m + 2), a2);
                a3 = fmaf(w[m + 3], bcast(hv, m + 3), a3);
            }
            acc = (a0 + a1) + (a2 + a3);
        }
        part[wave * 65 + lane] = acc;
        __syncthreads();   // waves 1..7 sprint ahead after this; wave 0 finishes the step

        if (wave == 0) {
            float r = zin;
            #pragma unroll
            for (int c = 0; c < 8; ++c) r += part[c * 65 + lane];
            // gather the 4 gates of unit jj into every lane (only jj<16 used)
            float zi = __shfl(r, jj);
            float zf = __shfl(r, 16 + jj);
            float zg = __shfl(r, 32 + jj);
            float zo = __shfl(r, 48 + jj);
            if (lane < 16) {
                float ig = sigm(zi), fg = sigm(zf), gg = tanh_fast(zg), og = sigm(zo);
                cval = fg * cval + ig * gg;
                float hv = og * tanh_fast(cval);
                const size_t oidx = (size_t)t * (2 * HID) + colOff + wg * 16 + lane;
                unsigned long long pk = ((unsigned long long)(tagBase + (unsigned)s) << 32)
                                      | (unsigned long long)__float_as_uint(hv);
                __hip_atomic_store(Hpair + oidx, pk, __ATOMIC_RELAXED, __HIP_MEMORY_SCOPE_AGENT);
                Hout[oidx] = hv;   // plain fp32 for downstream GEMMs
            }
        }
    }
}

// ---------------------------------------------------------------- pairwise MLP scores
__global__ __launch_bounds__(256)
void pairwise_kernel(const float* __restrict__ Ah, const float* __restrict__ Bd,
                     const float* __restrict__ w2, const float* __restrict__ b2,
                     float* __restrict__ out) {
    __shared__ __align__(16) float at[16 * 260];
    __shared__ __align__(16) float bt[16 * 260];
    __shared__ __align__(16) float wl[256];
    const int tid = threadIdx.x;
    const int i0 = blockIdx.y * 16, j0 = blockIdx.x * 16;
    for (int u = tid; u < 16 * 256; u += 256) {
        int r = u >> 8, m = u & 255;
        at[r * 260 + m] = Ah[(size_t)(i0 + r) * 256 + m];
        bt[r * 260 + m] = Bd[(size_t)(j0 + r) * 256 + m];
    }
    wl[tid] = w2[tid];
    __syncthreads();
    const int tj = tid & 15, ti = tid >> 4;
    float acc = b2[0];
    #pragma unroll 2
    for (int m = 0; m < 256; m += 4) {
        float4 a4 = *(const float4*)&at[ti * 260 + m];
        float4 b4 = *(const float4*)&bt[tj * 260 + m];
        float4 w4 = *(const float4*)&wl[m];
        acc += tanh_fast(a4.x + b4.x) * w4.x;
        acc += tanh_fast(a4.y + b4.y) * w4.y;
        acc += tanh_fast(a4.z + b4.z) * w4.z;
        acc += tanh_fast(a4.w + b4.w) * w4.w;
    }
    out[(size_t)(i0 + ti) * 1024 + (j0 + tj)] = acc;
}

// ---------------------------------------------------------------- launch
extern "C" void kernel_launch(void* const* d_in, const int* in_sizes, int n_in,
                              void* d_out, int out_size, void* d_ws, size_t ws_size,
                              hipStream_t stream) {
    const int*   wi    = (const int*)  d_in[0];
    const int*   pi    = (const int*)  d_in[1];
    const float* we    = (const float*)d_in[2];
    const float* pe    = (const float*)d_in[3];
    const float* wih0f = (const float*)d_in[4];
    const float* whh0f = (const float*)d_in[5];
    const float* b0f   = (const float*)d_in[6];
    const float* wih0r = (const float*)d_in[7];
    const float* whh0r = (const float*)d_in[8];
    const float* b0r   = (const float*)d_in[9];
    const float* wih1f = (const float*)d_in[10];
    const float* whh1f = (const float*)d_in[11];
    const float* b1f   = (const float*)d_in[12];
    const float* wih1r = (const float*)d_in[13];
    const float* whh1r = (const float*)d_in[14];
    const float* b1r   = (const float*)d_in[15];
    const float* W1    = (const float*)d_in[16];
    const float* bmlp1 = (const float*)d_in[17];
    const float* w2    = (const float*)d_in[18];
    const float* b2    = (const float*)d_in[19];
    float* out = (float*)d_out;

    char* wsb = (char*)d_ws;
    float* x  = (float*)(wsb + 512);          // 1024*400
    float* zA = x  + (size_t)1024 * 400;      // 1024*2048
    float* zB = zA + (size_t)1024 * 2048;     // 1024*2048
    float* h0 = zB + (size_t)1024 * 2048;     // 1024*1024
    float* h1 = h0 + (size_t)1024 * 1024;     // 1024*1024
    float* aH = h1 + (size_t)1024 * 1024;     // 1024*256
    float* bD = aH + (size_t)1024 * 256;      // 1024*256
    unsigned long long* Hpair = (unsigned long long*)(bD + (size_t)1024 * 256); // 1024*1024 u64

    embed_kernel<<<dim3(1024), dim3(128), 0, stream>>>(wi, pi, we, pe, x);

    // layer-0 input projections: [1024,400] @ [2048,400]^T
    gemm_bias<<<dim3(32, 16), dim3(256), 0, stream>>>(x, wih0f, b0f, zA, 1024, 2048, 400, 400, 400, 2048);
    gemm_bias<<<dim3(32, 16), dim3(256), 0, stream>>>(x, wih0r, b0r, zB, 1024, 2048, 400, 400, 400, 2048);

    lstm_layer<<<dim3(64), dim3(512), 0, stream>>>(zA, zB, whh0f, whh0r, Hpair, h0, 1u);

    // layer-1 input projections: [1024,1024] @ [2048,1024]^T
    gemm_bias<<<dim3(32, 16), dim3(256), 0, stream>>>(h0, wih1f, b1f, zA, 1024, 2048, 1024, 1024, 1024, 2048);
    gemm_bias<<<dim3(32, 16), dim3(256), 0, stream>>>(h0, wih1r, b1r, zB, 1024, 2048, 1024, 1024, 1024, 2048);

    lstm_layer<<<dim3(64), dim3(512), 0, stream>>>(zA, zB, whh1f, whh1r, Hpair, h1, 8192u);

    // head/dep projections: [1024,1024] @ [256,1024]^T (bmlp1 folded into aH)
    gemm_bias<<<dim3(4, 16), dim3(256), 0, stream>>>(h1, W1,        bmlp1,   aH, 1024, 256, 1024, 1024, 2048, 256);
    gemm_bias<<<dim3(4, 16), dim3(256), 0, stream>>>(h1, W1 + 1024, nullptr, bD, 1024, 256, 1024, 1024, 2048, 256);

    pairwise_kernel<<<dim3(64, 64), dim3(256), 0, stream>>>(aH, bD, w2, b2, out);
}